// Round 1
// baseline (21.127 us; speedup 1.0000x reference)
//
#include <hip/hip_runtime.h>

// InputVector: out[b,r,d] = sum_s( -0.5*((x[b,gi[r,s]]-mu[r,s,d])*exp(-ls[r,s,d]))^2
//                                  - ls[r,s,d] - 0.5*log(2*pi) )
// Shapes: B=128, F=1024, R=128, S=64, D=64. Output (B,R,D) fp32, flat b-major.

#define NB 128
#define NF 1024
#define NR 128
#define NS 64
#define ND 64
#define BTILE 32           // batch rows per block
#define HALF_LOG_2PI 0.9189385332046727f

__global__ __launch_bounds__(256)
void input_vector_kernel(const float* __restrict__ x,
                         const int*   __restrict__ gi,
                         const float* __restrict__ mu,
                         const float* __restrict__ ls,
                         float*       __restrict__ out) {
    const int r     = blockIdx.x;
    const int bBase = blockIdx.y * BTILE;
    const int t     = threadIdx.x;
    const int d     = t & 63;        // lane -> d index (coalesced mu/ls loads)
    const int w     = t >> 6;        // wave id 0..3 -> which 8 b-rows

    __shared__ int   gis[NS];
    __shared__ float xg[BTILE][NS];  // gathered x[b, gi[r,s]]

    if (t < NS) gis[t] = gi[r * NS + t];
    __syncthreads();

    // Gather 32 b-rows x 64 s into LDS. x is 512KB -> L2-resident.
    for (int k = t; k < BTILE * NS; k += 256) {
        const int bl = k >> 6;
        const int s  = k & 63;
        xg[bl][s] = x[(bBase + bl) * NF + gis[s]];
    }
    __syncthreads();

    const float* mu_r = mu + r * NS * ND;
    const float* ls_r = ls + r * NS * ND;

    float acc[8] = {0.f, 0.f, 0.f, 0.f, 0.f, 0.f, 0.f, 0.f};
    float csum = 0.f;

    #pragma unroll 4
    for (int s = 0; s < NS; ++s) {
        const float m  = mu_r[s * ND + d];
        const float l  = ls_r[s * ND + d];
        const float iv = __expf(-l);     // exp(-log_sigma)
        csum += l;
        #pragma unroll
        for (int i = 0; i < 8; ++i) {
            // LDS read is wave-uniform (same addr for all 64 lanes) -> broadcast
            const float z = (xg[w * 8 + i][s] - m) * iv;
            acc[i] = fmaf(z, z, acc[i]);
        }
    }

    const float cterm = -csum - (float)NS * HALF_LOG_2PI;
    #pragma unroll
    for (int i = 0; i < 8; ++i) {
        const int b = bBase + w * 8 + i;
        out[(b * NR + r) * ND + d] = -0.5f * acc[i] + cterm;
    }
}

extern "C" void kernel_launch(void* const* d_in, const int* in_sizes, int n_in,
                              void* d_out, int out_size, void* d_ws, size_t ws_size,
                              hipStream_t stream) {
    const float* x  = (const float*)d_in[0];
    const int*   gi = (const int*)  d_in[1];
    const float* mu = (const float*)d_in[2];
    const float* ls = (const float*)d_in[3];
    float*       out = (float*)d_out;

    dim3 grid(NR, NB / BTILE);   // (128, 4)
    dim3 block(256);
    input_vector_kernel<<<grid, block, 0, stream>>>(x, gi, mu, ls, out);
}

// Round 2
// 17.372 us; speedup vs baseline: 1.2162x; 1.2162x over previous
//
#include <hip/hip_runtime.h>

// InputVector: out[b,r,d] = sum_s( -0.5*((x[b,gi[r,s]]-mu[r,s,d])*exp(-ls[r,s,d]))^2
//                                  - ls[r,s,d] - 0.5*log(2*pi) )
// Shapes: B=128, F=1024, R=128, S=64, D=64. Output (B,R,D) fp32, b-major.
//
// R1 -> R2: occupancy fix. 2 b-rows per thread (was 8), BTILE=8, grid (128,16)
// = 2048 blocks x 4 waves = 8192 waves = 32 waves/CU (was 8/CU, 18% occupancy).

#define NB 128
#define NF 1024
#define NR 128
#define NS 64
#define ND 64
#define BTILE 8            // batch rows per block (4 waves x 2 rows/thread)
#define HALF_LOG_2PI 0.9189385332046727f

__global__ __launch_bounds__(256)
void input_vector_kernel(const float* __restrict__ x,
                         const int*   __restrict__ gi,
                         const float* __restrict__ mu,
                         const float* __restrict__ ls,
                         float*       __restrict__ out) {
    const int r     = blockIdx.x;
    const int bBase = blockIdx.y * BTILE;
    const int t     = threadIdx.x;
    const int d     = t & 63;        // lane -> d index (coalesced mu/ls loads)
    const int w     = t >> 6;        // wave id 0..3 -> which 2 b-rows

    __shared__ int   gis[NS];
    __shared__ float xg[BTILE][NS];  // gathered x[b, gi[r,s]]

    if (t < NS) gis[t] = gi[r * NS + t];
    __syncthreads();

    // Gather 8 b-rows x 64 s into LDS (512 elems, 2 per thread). x is 512KB -> L2.
    for (int k = t; k < BTILE * NS; k += 256) {
        const int bl = k >> 6;
        const int s  = k & 63;
        xg[bl][s] = x[(bBase + bl) * NF + gis[s]];
    }
    __syncthreads();

    const float* mu_r = mu + r * NS * ND + d;
    const float* ls_r = ls + r * NS * ND + d;

    const int b0 = w * 2;
    float acc0 = 0.f, acc1 = 0.f, csum = 0.f;

    #pragma unroll 8
    for (int s = 0; s < NS; ++s) {
        const float m  = mu_r[s * ND];
        const float l  = ls_r[s * ND];
        const float iv = __expf(-l);     // exp(-log_sigma), TRANS pipe
        csum += l;
        // LDS reads are wave-uniform (broadcast); unroll lets compiler merge
        // consecutive-s reads into ds_read_b128.
        const float z0 = (xg[b0 + 0][s] - m) * iv;
        const float z1 = (xg[b0 + 1][s] - m) * iv;
        acc0 = fmaf(z0, z0, acc0);
        acc1 = fmaf(z1, z1, acc1);
    }

    const float cterm = -csum - (float)NS * HALF_LOG_2PI;
    out[((bBase + b0 + 0) * NR + r) * ND + d] = -0.5f * acc0 + cterm;
    out[((bBase + b0 + 1) * NR + r) * ND + d] = -0.5f * acc1 + cterm;
}

extern "C" void kernel_launch(void* const* d_in, const int* in_sizes, int n_in,
                              void* d_out, int out_size, void* d_ws, size_t ws_size,
                              hipStream_t stream) {
    const float* x  = (const float*)d_in[0];
    const int*   gi = (const int*)  d_in[1];
    const float* mu = (const float*)d_in[2];
    const float* ls = (const float*)d_in[3];
    float*       out = (float*)d_out;

    dim3 grid(NR, NB / BTILE);   // (128, 16) = 2048 blocks
    dim3 block(256);
    input_vector_kernel<<<grid, block, 0, stream>>>(x, gi, mu, ls, out);
}

// Round 3
// 15.175 us; speedup vs baseline: 1.3922x; 1.1448x over previous
//
#include <hip/hip_runtime.h>

// InputVector: out[b,r,d] = sum_s( -0.5*((x[b,gi[r,s]]-mu[r,s,d])*exp(-ls[r,s,d]))^2
//                                  - ls[r,s,d] - 0.5*log(2*pi) )
// Shapes: B=128, F=1024, R=128, S=64, D=64. Output (B,R,D) fp32, b-major.
//
// R2 -> R3: s-split across waves. Each wave owns 16 s-values (all 8 b-rows),
// so mu/ls are read exactly once per block (was 4x wave-redundant -> L1-BW
// bound ~6.8us/CU). Cross-wave reduce via small LDS partials.

#define NB 128
#define NF 1024
#define NR 128
#define NS 64
#define ND 64
#define BTILE 8            // batch rows per block; every wave covers all 8
#define SW 16              // s-values per wave
#define HALF_LOG_2PI 0.9189385332046727f

__global__ __launch_bounds__(256)
void input_vector_kernel(const float* __restrict__ x,
                         const int*   __restrict__ gi,
                         const float* __restrict__ mu,
                         const float* __restrict__ ls,
                         float*       __restrict__ out) {
    const int r     = blockIdx.x;
    const int bBase = blockIdx.y * BTILE;
    const int t     = threadIdx.x;
    const int d     = t & 63;        // lane -> d (coalesced mu/ls loads)
    const int w     = t >> 6;        // wave id 0..3 -> s in [w*16, w*16+16)

    __shared__ int   gis[NS];
    __shared__ float xg[BTILE][NS];        // gathered x[b, gi[r,s]]
    __shared__ float part[4][BTILE][ND];   // per-wave partial sums

    if (t < NS) gis[t] = gi[r * NS + t];
    __syncthreads();

    // Gather 8 b-rows x 64 s into LDS (512 elems, 2 per thread). x: 512KB -> L2.
    for (int k = t; k < BTILE * NS; k += 256) {
        xg[k >> 6][k & 63] = x[(bBase + (k >> 6)) * NF + gis[k & 63]];
    }
    __syncthreads();

    const float* mu_p = mu + (r * NS + w * SW) * ND + d;
    const float* ls_p = ls + (r * NS + w * SW) * ND + d;

    float acc[BTILE] = {0.f, 0.f, 0.f, 0.f, 0.f, 0.f, 0.f, 0.f};
    float csum = 0.f;

    #pragma unroll 4
    for (int s = 0; s < SW; ++s) {
        const float m  = mu_p[s * ND];
        const float l  = ls_p[s * ND];
        const float iv = __expf(-l);           // TRANS pipe
        csum += l;
        const int ss = w * SW + s;
        #pragma unroll
        for (int b = 0; b < BTILE; ++b) {
            // wave-uniform LDS read -> broadcast, conflict-free
            const float z = (xg[b][ss] - m) * iv;
            acc[b] = fmaf(z, z, acc[b]);
        }
    }

    // Per-wave partial: -0.5*acc - csum_w  (csum identical across b within wave)
    #pragma unroll
    for (int b = 0; b < BTILE; ++b) {
        part[w][b][d] = fmaf(-0.5f, acc[b], -csum);   // lanes: consecutive d
    }
    __syncthreads();

    // 512 outputs, 2 per thread: sum the 4 wave partials + constant.
    #pragma unroll
    for (int k0 = 0; k0 < 2; ++k0) {
        const int k  = t + k0 * 256;
        const int b  = k >> 6;
        const int dd = k & 63;
        const float v = part[0][b][dd] + part[1][b][dd]
                      + part[2][b][dd] + part[3][b][dd]
                      - (float)NS * HALF_LOG_2PI;
        out[((bBase + b) * NR + r) * ND + dd] = v;
    }
}

extern "C" void kernel_launch(void* const* d_in, const int* in_sizes, int n_in,
                              void* d_out, int out_size, void* d_ws, size_t ws_size,
                              hipStream_t stream) {
    const float* x  = (const float*)d_in[0];
    const int*   gi = (const int*)  d_in[1];
    const float* mu = (const float*)d_in[2];
    const float* ls = (const float*)d_in[3];
    float*       out = (float*)d_out;

    dim3 grid(NR, NB / BTILE);   // (128, 16) = 2048 blocks, 32 waves/CU
    dim3 block(256);
    input_vector_kernel<<<grid, block, 0, stream>>>(x, gi, mu, ls, out);
}

// Round 4
// 10.198 us; speedup vs baseline: 2.0717x; 1.4881x over previous
//
#include <hip/hip_runtime.h>
#include <hip/hip_bf16.h>

// InputVector via MFMA: expand -0.5*((x-m)*iv)^2 - l - c  with iv=exp(-l) into
//   A[s,d]*x2[b,s] + C[s,d]*x[b,s] + e[s,d],  A=-0.5*iv^2, C=m*iv^2,
//   e=-0.5*iv^2*m^2 - l - 0.5*log(2pi)
// => per region r: out_r[b,d] = [x2|x] (32x128) . [A;C] (128x64) + E[d]
// One block = (r, 32 b-rows). K interleaved as (x2_s, x_s) pairs so gather and
// prep each write ONE packed b32 per element pair; same k-permutation on both
// operands keeps the contraction valid. XOR swizzle ((row&7)<<4 on bytes) makes
// the ds_read_b128 fragment reads conflict-free (G4 / T2).

#define NB 128
#define NF 1024
#define NR 128
#define NS 64
#define ND 64
#define BT 32               // b-rows per block
#define HALF_LOG_2PI 0.9189385332046727f

typedef __attribute__((ext_vector_type(8))) short bf16x8;
typedef __attribute__((ext_vector_type(4))) float f32x4;

static __device__ __forceinline__ unsigned int f2bf(float f) {
    __hip_bfloat16 h = __float2bfloat16(f);
    return (unsigned int)__builtin_bit_cast(unsigned short, h);
}

__global__ __launch_bounds__(256)
void iv_mfma_kernel(const float* __restrict__ x,
                    const int*   __restrict__ gi,
                    const float* __restrict__ mu,
                    const float* __restrict__ ls,
                    float*       __restrict__ out) {
    const int r     = blockIdx.x;
    const int bBase = blockIdx.y * BT;
    const int t     = threadIdx.x;
    const int lane  = t & 63;
    const int w     = t >> 6;

    __shared__ int   ldsX[BT * 64];   // [b][s]: packed (lo=bf16(x^2), hi=bf16(x)), swizzled
    __shared__ int   ldsB[ND * 64];   // [d][s]: packed (lo=bf16(A),   hi=bf16(C)), swizzled
    __shared__ float Ep[4][ND];       // per-wave E partials

    // ---- phase 1a: gather x for 32 b-rows; write packed (x2,x) bf16 pairs ----
    {
        const int s   = lane;                 // fixed s per thread
        const int idx = gi[r * NS + s];       // gather column
        const float* xp = x + (bBase + w) * NF + idx;
        #pragma unroll
        for (int p = 0; p < 8; ++p) {
            const int b = p * 4 + w;          // b-row within tile
            const float v  = xp[p * 4 * NF];
            const float v2 = v * v;
            const int pack = (int)(f2bf(v2) | (f2bf(v) << 16));
            ldsX[(b * 64 + s) ^ ((b & 7) << 2)] = pack;   // 2-way banks: free
        }
    }

    // ---- phase 1b: coefficients A,C,e for 16 s-values per wave (lane = d) ----
    {
        const int d = lane;
        const float* mu_p = mu + (r * NS + w * 16) * ND + d;
        const float* ls_p = ls + (r * NS + w * 16) * ND + d;
        float Epart = 0.f;
        #pragma unroll 4
        for (int i = 0; i < 16; ++i) {
            const int s = w * 16 + i;
            const float m   = mu_p[i * ND];
            const float l   = ls_p[i * ND];
            const float ivv = __expf(-l);
            const float iv2 = ivv * ivv;
            const float A   = -0.5f * iv2;
            const float C   = m * iv2;
            Epart += fmaf(-0.5f * C, m, -l - HALF_LOG_2PI);
            const int pack = (int)(f2bf(A) | (f2bf(C) << 16));
            ldsB[(d * 64 + s) ^ ((d & 7) << 2)] = pack;   // ~8-way on 16 writes: ok
        }
        Ep[w][d] = Epart;
    }

    __syncthreads();

    // ---- phase 2: MFMA. wave w: m-tile mt=w&1 (16 b's), n-tiles {2*(w>>1),+1} ----
    const int mt = w & 1;
    const int nh = w >> 1;
    const short* sX = (const short*)ldsX;
    const short* sB = (const short*)ldsB;

    f32x4 acc0 = {0.f, 0.f, 0.f, 0.f};
    f32x4 acc1 = {0.f, 0.f, 0.f, 0.f};

    const int arow  = mt * 16 + (lane & 15);
    const int kofs  = (lane >> 4) * 8;          // 8 bf16 per lane per k-step
    const int brow0 = nh * 32 + (lane & 15);
    const int brow1 = brow0 + 16;

    #pragma unroll
    for (int kc = 0; kc < 4; ++kc) {
        const int ke = kc * 32 + kofs;
        const bf16x8 a  = *(const bf16x8*)&sX[(arow  * 128 + ke) ^ ((arow  & 7) << 3)];
        const bf16x8 b0 = *(const bf16x8*)&sB[(brow0 * 128 + ke) ^ ((brow0 & 7) << 3)];
        const bf16x8 b1 = *(const bf16x8*)&sB[(brow1 * 128 + ke) ^ ((brow1 & 7) << 3)];
        acc0 = __builtin_amdgcn_mfma_f32_16x16x32_bf16(a, b0, acc0, 0, 0, 0);
        acc1 = __builtin_amdgcn_mfma_f32_16x16x32_bf16(a, b1, acc1, 0, 0, 0);
    }

    // ---- epilogue: out[(b)*NR*ND + r*ND + d] = acc + E[d] ----
    // C/D layout (m89): col = lane&15 -> n(=d), row = (lane>>4)*4 + i -> m(=b)
    {
        const int d0 = nh * 32 + (lane & 15);
        const int d1 = d0 + 16;
        const float E0 = Ep[0][d0] + Ep[1][d0] + Ep[2][d0] + Ep[3][d0];
        const float E1 = Ep[0][d1] + Ep[1][d1] + Ep[2][d1] + Ep[3][d1];
        const int brow = bBase + mt * 16 + (lane >> 4) * 4;
        #pragma unroll
        for (int i = 0; i < 4; ++i) {
            float* op = out + ((brow + i) * NR + r) * ND;
            op[d0] = acc0[i] + E0;
            op[d1] = acc1[i] + E1;
        }
    }
}

extern "C" void kernel_launch(void* const* d_in, const int* in_sizes, int n_in,
                              void* d_out, int out_size, void* d_ws, size_t ws_size,
                              hipStream_t stream) {
    const float* x  = (const float*)d_in[0];
    const int*   gi = (const int*)  d_in[1];
    const float* mu = (const float*)d_in[2];
    const float* ls = (const float*)d_in[3];
    float*       out = (float*)d_out;

    dim3 grid(NR, NB / BT);   // (128, 4) = 512 blocks
    dim3 block(256);
    iv_mfma_kernel<<<grid, block, 0, stream>>>(x, gi, mu, ls, out);
}

// Round 5
// 10.052 us; speedup vs baseline: 2.1017x; 1.0145x over previous
//
#include <hip/hip_runtime.h>
#include <hip/hip_bf16.h>

// InputVector via MFMA: expand -0.5*((x-m)*iv)^2 - l - c  with iv=exp(-l) into
//   A[s,d]*x2[b,s] + C[s,d]*x[b,s] + e[s,d],  A=-0.5*iv^2, C=m*iv^2
// => per region r: out_r[b,d] = [x2|x] (32x128) . [A;C] (128x64) + E[d]
//
// R4 -> R5: occupancy 2x. 512-thread blocks (8 waves), grid (128,4) ->
// 16 waves/CU (was 8). Each wave: one 16x16 output tile, full K=128 (4 MFMA).
// Per-thread work halves (4 gathers, 8 coeff s-values).

#define NB 128
#define NF 1024
#define NR 128
#define NS 64
#define ND 64
#define BT 32               // b-rows per block
#define HALF_LOG_2PI 0.9189385332046727f

typedef __attribute__((ext_vector_type(8))) short bf16x8;
typedef __attribute__((ext_vector_type(4))) float f32x4;

static __device__ __forceinline__ unsigned int f2bf(float f) {
    __hip_bfloat16 h = __float2bfloat16(f);
    return (unsigned int)__builtin_bit_cast(unsigned short, h);
}

__global__ __launch_bounds__(512)
void iv_mfma_kernel(const float* __restrict__ x,
                    const int*   __restrict__ gi,
                    const float* __restrict__ mu,
                    const float* __restrict__ ls,
                    float*       __restrict__ out) {
    const int r     = blockIdx.x;
    const int bBase = blockIdx.y * BT;
    const int t     = threadIdx.x;
    const int lane  = t & 63;
    const int w     = t >> 6;        // wave 0..7

    __shared__ int   ldsX[BT * 64];   // [b][s]: packed (lo=bf16(x^2), hi=bf16(x)), swizzled
    __shared__ int   ldsB[ND * 64];   // [d][s]: packed (lo=bf16(A),   hi=bf16(C)), swizzled
    __shared__ float Ep[8][ND];       // per-wave E partials

    // ---- phase 1a: gather x for 32 b-rows; write packed (x2,x) bf16 pairs ----
    {
        const int s   = lane;                 // fixed s per thread
        const int idx = gi[r * NS + s];       // gather column
        const float* xp = x + (bBase + w) * NF + idx;
        #pragma unroll
        for (int p = 0; p < 4; ++p) {
            const int b = p * 8 + w;          // b-row within tile
            const float v  = xp[p * 8 * NF];
            const int pack = (int)(f2bf(v * v) | (f2bf(v) << 16));
            ldsX[(b * 64 + s) ^ ((b & 7) << 2)] = pack;
        }
    }

    // ---- phase 1b: coefficients A,C,e for 8 s-values per wave (lane = d) ----
    {
        const int d = lane;
        const float* mu_p = mu + (r * NS + w * 8) * ND + d;
        const float* ls_p = ls + (r * NS + w * 8) * ND + d;
        float Epart = 0.f;
        #pragma unroll
        for (int i = 0; i < 8; ++i) {
            const int s = w * 8 + i;
            const float m   = mu_p[i * ND];
            const float l   = ls_p[i * ND];
            const float ivv = __expf(-l);
            const float iv2 = ivv * ivv;
            const float A   = -0.5f * iv2;
            const float C   = m * iv2;
            Epart += fmaf(-0.5f * C, m, -l - HALF_LOG_2PI);
            ldsB[(d * 64 + s) ^ ((d & 7) << 2)] = (int)(f2bf(A) | (f2bf(C) << 16));
        }
        Ep[w][d] = Epart;
    }

    __syncthreads();

    // ---- phase 2: wave w -> m-tile mt=w&1 (16 b's), n-tile nt=w>>1 (16 d's) ----
    const int mt = w & 1;
    const int nt = w >> 1;
    const short* sX = (const short*)ldsX;
    const short* sB = (const short*)ldsB;

    f32x4 acc = {0.f, 0.f, 0.f, 0.f};
    const int arow = mt * 16 + (lane & 15);
    const int brow = nt * 16 + (lane & 15);
    const int kofs = (lane >> 4) * 8;          // 8 bf16 per lane per k-step

    #pragma unroll
    for (int kc = 0; kc < 4; ++kc) {
        const int ke = kc * 32 + kofs;
        const bf16x8 a = *(const bf16x8*)&sX[(arow * 128 + ke) ^ ((arow & 7) << 3)];
        const bf16x8 b = *(const bf16x8*)&sB[(brow * 128 + ke) ^ ((brow & 7) << 3)];
        acc = __builtin_amdgcn_mfma_f32_16x16x32_bf16(a, b, acc, 0, 0, 0);
    }

    // ---- epilogue: C/D layout col = lane&15 -> d, row = (lane>>4)*4 + i -> b ----
    {
        const int d0 = nt * 16 + (lane & 15);
        float E0 = 0.f;
        #pragma unroll
        for (int p = 0; p < 8; ++p) E0 += Ep[p][d0];
        const int bo = bBase + mt * 16 + (lane >> 4) * 4;
        #pragma unroll
        for (int i = 0; i < 4; ++i) {
            out[((bo + i) * NR + r) * ND + d0] = acc[i] + E0;
        }
    }
}

extern "C" void kernel_launch(void* const* d_in, const int* in_sizes, int n_in,
                              void* d_out, int out_size, void* d_ws, size_t ws_size,
                              hipStream_t stream) {
    const float* x  = (const float*)d_in[0];
    const int*   gi = (const int*)  d_in[1];
    const float* mu = (const float*)d_in[2];
    const float* ls = (const float*)d_in[3];
    float*       out = (float*)d_out;

    dim3 grid(NR, NB / BT);   // (128, 4) = 512 blocks x 8 waves
    dim3 block(512);
    iv_mfma_kernel<<<grid, block, 0, stream>>>(x, gi, mu, ls, out);
}